// Round 3
// baseline (490.037 us; speedup 1.0000x reference)
//
#include <hip/hip_runtime.h>

// Problem constants
#define B_SZ 65536
#define NH   100

typedef __bf16 bf16_t;
typedef __bf16 bf16x8 __attribute__((ext_vector_type(8)));
typedef float  f32x4  __attribute__((ext_vector_type(4)));

// ---- d_ws bf16 fragment layout (elements), N padded to 112 (7 n-tiles) ----
// frag f=(nt*KC+kc): lane holds W[kc*32+Q*8+j][nt*16+c], j contiguous (b128)
#define SZ_W2 14336            // 7nt * 4kc * 512
#define SZ_W3 8192             // 4nt * 4kc * 512
#define SZ_W1 7168             // 7nt * 2kc * 512 (per net per z-block)
#define OFF_W3   28672         // after W2S,W2T
#define OFF_W1   45056         // after W3S,W3T; block b: S at +b*2*SZ_W1, T at +SZ_W1
#define WS_TOTAL 145408        // elements (290816 bytes)

__global__ void prep_weights(const float* __restrict__ sW1, const float* __restrict__ sW2,
                             const float* __restrict__ sW3, const float* __restrict__ tW1,
                             const float* __restrict__ tW2, const float* __restrict__ tW3,
                             bf16_t* __restrict__ ws) {
  int idx = blockIdx.x * 256 + threadIdx.x;
  if (idx >= WS_TOTAL) return;
  float v = 0.f;
  if (idx < 2 * SZ_W2) {                    // W2: [100,100] -> K128 x N112 frags
    const float* W = (idx < SZ_W2) ? sW2 : tW2;
    int l = (idx < SZ_W2) ? idx : idx - SZ_W2;
    int j = l & 7, ln = (l >> 3) & 63, kc = (l >> 9) & 3, nt = l >> 11;   // nt 0..6
    int k = kc * 32 + (ln >> 4) * 8 + j;
    int n = nt * 16 + (ln & 15);
    v = (k < NH && n < NH) ? W[k * NH + n] : 0.f;
  } else if (idx < OFF_W1) {                // W3: [100,64] -> K128 x N64 frags
    int l = idx - OFF_W3;
    const float* W = (l < SZ_W3) ? sW3 : tW3;
    l &= (SZ_W3 - 1);
    int j = l & 7, ln = (l >> 3) & 63, kc = (l >> 9) & 3, nt = l >> 11;   // nt 0..3
    int k = kc * 32 + (ln >> 4) * 8 + j;
    int n = nt * 16 + (ln & 15);
    v = (k < NH) ? W[k * 64 + n] : 0.f;
  } else {                                  // W1 blocks 0..6: [64,100] -> K64 x N112 frags
    int l = idx - OFF_W1;
    int b = l / (2 * SZ_W1);
    int r2 = l - b * 2 * SZ_W1;
    const float* W = (r2 < SZ_W1) ? sW1 : tW1;
    int w = (r2 < SZ_W1) ? r2 : r2 - SZ_W1;
    int j = w & 7, ln = (w >> 3) & 63, kc = (w >> 9) & 1, nt = w >> 10;   // nt 0..6
    int k = kc * 32 + (ln >> 4) * 8 + j;    // 0..63
    int n = nt * 16 + (ln & 15);
    v = (n < NH) ? W[(b * 64 + k) * NH + n] : 0.f;
  }
  ws[idx] = (bf16_t)v;
}

// async global->LDS 16B per lane: gptr per-lane, lptr wave-uniform base (+lane*16 implicit)
__device__ __forceinline__ void gload_lds16(const void* gptr, void* lptr) {
  __builtin_amdgcn_global_load_lds(
      (const __attribute__((address_space(1))) unsigned int*)gptr,
      (__attribute__((address_space(3))) unsigned int*)lptr, 16, 0, 0);
}

struct __align__(16) SMem {
  bf16_t w2[2 * SZ_W2];   // S at 0, T at SZ_W2           (57344 B)
  bf16_t w3[2 * SZ_W3];   // S at 0, T at SZ_W3           (32768 B)
  bf16_t hb[8][16 * 136]; // per-wave transpose buffer    (34816 B)
};                        // total 124928 B -> 1 block/CU, 8 waves

// 256 blocks x 512 threads (8 waves); each wave owns 32 batch rows (2 m-tiles).
// One generation; zero barriers inside the step loop (W1 update streams from L1/L2).
__global__ __launch_bounds__(512, 2) void flow_kernel(
    const float* __restrict__ e,
    const float* __restrict__ sb1, const float* __restrict__ sb2, const float* __restrict__ sb3,
    const float* __restrict__ tb1, const float* __restrict__ tb2, const float* __restrict__ tb3,
    const bf16_t* __restrict__ wf,
    float* __restrict__ out) {
  __shared__ SMem sm;

  const int tid  = threadIdx.x;
  const int wave = tid >> 6;
  const int lane = tid & 63;
  const int c    = lane & 15;   // C/D col, A-frag m-row
  const int Q    = lane >> 4;   // quad
  const int rowBase = blockIdx.x * 256 + wave * 32;

  bf16_t* const myh = &sm.hb[wave][0];

  // ---- initial load: W2S,W2T,W3S,W3T = 90112 B = 88 x 1KB chunks over 8 waves
  {
    const char* g = (const char*)wf;
    char* l = (char*)&sm;
    #pragma unroll
    for (int t = 0; t < 11; ++t) {
      const int ch = wave * 11 + t;
      gload_lds16(g + ch * 1024 + lane * 16, l + ch * 1024);
    }
  }

  // ---- bias registers ----
  float b2S[7], b2T[7], b3S[4], b3T[4];
  #pragma unroll
  for (int nt = 0; nt < 7; ++nt) {
    const int n = nt * 16 + c;
    b2S[nt] = (n < NH) ? sb2[n] : 0.f;
    b2T[nt] = (n < NH) ? tb2[n] : 0.f;
  }
  #pragma unroll
  for (int nt = 0; nt < 4; ++nt) { b3S[nt] = sb3[nt * 16 + c]; b3T[nt] = tb3[nt * 16 + c]; }

  // persistent incremental layer-1 pre-activations (+b1), both nets
  f32x4 acc1S[2][7], acc1T[2][7];
  #pragma unroll
  for (int nt = 0; nt < 7; ++nt) {
    const int n = nt * 16 + c;
    const float b1s = (n < NH) ? sb1[n] : 0.f;
    const float b1t = (n < NH) ? tb1[n] : 0.f;
    const f32x4 vs = {b1s, b1s, b1s, b1s};
    const f32x4 vt = {b1t, b1t, b1t, b1t};
    #pragma unroll
    for (int mt = 0; mt < 2; ++mt) { acc1S[mt][nt] = vs; acc1T[mt][nt] = vt; }
  }
  float ldacc[2][4] = {0.f, 0.f, 0.f, 0.f, 0.f, 0.f, 0.f, 0.f};

  __syncthreads();   // weights resident; no further barriers in the whole kernel

  // one net: acc1 -> relu -> LDS -> A-frags -> L2 -> relu -> LDS -> A-frags -> L3 -> acc3
  auto run_net = [&](const f32x4 (&acc1)[2][7], const bf16_t* __restrict__ w2f,
                     const bf16_t* __restrict__ w3f, const float (&b2r)[7],
                     const float (&b3r)[4], f32x4 (&acc3)[2][4]) {
    f32x4 acc2[2][7];
    bf16x8 af[2][4];
    // L2 A-feed (h1), zero-pad cols 112..127 for the kc=3 chunk
    #pragma unroll
    for (int mt = 0; mt < 2; ++mt) {
      #pragma unroll
      for (int nt = 0; nt < 7; ++nt)
        #pragma unroll
        for (int r = 0; r < 4; ++r)
          myh[(Q * 4 + r) * 136 + nt * 16 + c] = (bf16_t)fmaxf(acc1[mt][nt][r], 0.f);
      #pragma unroll
      for (int r = 0; r < 4; ++r)
        myh[(Q * 4 + r) * 136 + 112 + c] = (bf16_t)0.f;
      #pragma unroll
      for (int kc = 0; kc < 4; ++kc)
        af[mt][kc] = *(const bf16x8*)(myh + c * 136 + kc * 32 + Q * 8);
    }
    #pragma unroll
    for (int nt = 0; nt < 7; ++nt) {
      const f32x4 bv = {b2r[nt], b2r[nt], b2r[nt], b2r[nt]};
      acc2[0][nt] = bv; acc2[1][nt] = bv;
    }
    #pragma unroll
    for (int nt = 0; nt < 7; ++nt)
      #pragma unroll
      for (int kc = 0; kc < 4; ++kc) {
        const bf16x8 bfr = *(const bf16x8*)(w2f + ((nt * 4 + kc) * 64 + lane) * 8);
        #pragma unroll
        for (int mt = 0; mt < 2; ++mt)
          acc2[mt][nt] = __builtin_amdgcn_mfma_f32_16x16x32_bf16(af[mt][kc], bfr, acc2[mt][nt], 0, 0, 0);
      }
    // L3 A-feed (h2); pad cols stay zero from h1 write
    #pragma unroll
    for (int mt = 0; mt < 2; ++mt) {
      #pragma unroll
      for (int nt = 0; nt < 7; ++nt)
        #pragma unroll
        for (int r = 0; r < 4; ++r)
          myh[(Q * 4 + r) * 136 + nt * 16 + c] = (bf16_t)fmaxf(acc2[mt][nt][r], 0.f);
      #pragma unroll
      for (int kc = 0; kc < 4; ++kc)
        af[mt][kc] = *(const bf16x8*)(myh + c * 136 + kc * 32 + Q * 8);
    }
    #pragma unroll
    for (int nt = 0; nt < 4; ++nt) {
      const f32x4 bv = {b3r[nt], b3r[nt], b3r[nt], b3r[nt]};
      acc3[0][nt] = bv; acc3[1][nt] = bv;
    }
    #pragma unroll
    for (int nt = 0; nt < 4; ++nt)
      #pragma unroll
      for (int kc = 0; kc < 4; ++kc) {
        const bf16x8 bfr = *(const bf16x8*)(w3f + ((nt * 4 + kc) * 64 + lane) * 8);
        #pragma unroll
        for (int mt = 0; mt < 2; ++mt)
          acc3[mt][nt] = __builtin_amdgcn_mfma_f32_16x16x32_bf16(af[mt][kc], bfr, acc3[mt][nt], 0, 0, 0);
      }
  };

  for (int i = 0; i < 8; ++i) {
    // prefetch e for this step into registers (consumed in epilogue, ~2 GEMMs later)
    float ev[2][4][4];
    #pragma unroll
    for (int mt = 0; mt < 2; ++mt)
      #pragma unroll
      for (int r = 0; r < 4; ++r) {
        const int ebase = (rowBase + mt * 16 + Q * 4 + r) * 512 + i * 64;
        #pragma unroll
        for (int nt = 0; nt < 4; ++nt)
          ev[mt][r][nt] = e[ebase + nt * 16 + c];
      }

    f32x4 acc3S[2][4], acc3T[2][4];
    run_net(acc1S, sm.w2,         sm.w3,         b2S, b3S, acc3S);
    run_net(acc1T, sm.w2 + SZ_W2, sm.w3 + SZ_W3, b2T, b3T, acc3T);

    // ---- epilogue: s,t = sigmoid; z = exp(s)*e + t; logdet += sum(s) ----
    bf16x8 zfa[2][2];
    #pragma unroll
    for (int mt = 0; mt < 2; ++mt) {
      #pragma unroll
      for (int r = 0; r < 4; ++r) {
        const int obase = (rowBase + mt * 16 + Q * 4 + r) * 512 + i * 64;
        float ssum = 0.f;
        #pragma unroll
        for (int nt = 0; nt < 4; ++nt) {
          const int col = nt * 16 + c;
          const float sv = 1.f / (1.f + __expf(-acc3S[mt][nt][r]));
          const float tv = 1.f / (1.f + __expf(-acc3T[mt][nt][r]));
          const float zv = __expf(sv) * ev[mt][r][nt] + tv;
          __builtin_nontemporal_store(zv, &out[obase + col]);
          myh[(Q * 4 + r) * 136 + col] = (bf16_t)zv;
          ssum += sv;
        }
        ssum += __shfl_xor(ssum, 1);
        ssum += __shfl_xor(ssum, 2);
        ssum += __shfl_xor(ssum, 4);
        ssum += __shfl_xor(ssum, 8);
        ldacc[mt][r] += ssum;
      }
      #pragma unroll
      for (int kc = 0; kc < 2; ++kc)
        zfa[mt][kc] = *(const bf16x8*)(myh + c * 136 + kc * 32 + Q * 8);
    }

    // ---- incremental layer-1 update: acc1 += z_i @ W1[block i] ----
    // W1 fragments streamed straight from global (uniform base + lane*16 ->
    // coalesced dwordx4; 28 KB/step shared by all 8 waves -> L1-resident).
    if (i < 7) {
      const bf16_t* __restrict__ w1g = wf + OFF_W1 + i * 2 * SZ_W1;
      #pragma unroll
      for (int nt = 0; nt < 7; ++nt)
        #pragma unroll
        for (int kc = 0; kc < 2; ++kc) {
          const bf16x8 bS = *(const bf16x8*)(w1g + ((nt * 2 + kc) * 64 + lane) * 8);
          const bf16x8 bT = *(const bf16x8*)(w1g + SZ_W1 + ((nt * 2 + kc) * 64 + lane) * 8);
          #pragma unroll
          for (int mt = 0; mt < 2; ++mt) {
            acc1S[mt][nt] = __builtin_amdgcn_mfma_f32_16x16x32_bf16(zfa[mt][kc], bS, acc1S[mt][nt], 0, 0, 0);
            acc1T[mt][nt] = __builtin_amdgcn_mfma_f32_16x16x32_bf16(zfa[mt][kc], bT, acc1T[mt][nt], 0, 0, 0);
          }
        }
    }
  }

  // log_det: per (mt,r) replicated across 16 c-lanes; lane c==0 writes
  if (c == 0) {
    #pragma unroll
    for (int mt = 0; mt < 2; ++mt)
      #pragma unroll
      for (int r = 0; r < 4; ++r)
        out[B_SZ * 512 + rowBase + mt * 16 + Q * 4 + r] = ldacc[mt][r];
  }
}

extern "C" void kernel_launch(void* const* d_in, const int* in_sizes, int n_in,
                              void* d_out, int out_size, void* d_ws, size_t ws_size,
                              hipStream_t stream) {
  (void)in_sizes; (void)n_in; (void)out_size; (void)ws_size;
  const float* e   = (const float*)d_in[0];
  // d_in[1] is C (fixed strict-upper-triangular structure; encoded in the algorithm)
  const float* sW1 = (const float*)d_in[2];
  const float* sb1 = (const float*)d_in[3];
  const float* sW2 = (const float*)d_in[4];
  const float* sb2 = (const float*)d_in[5];
  const float* sW3 = (const float*)d_in[6];
  const float* sb3 = (const float*)d_in[7];
  const float* tW1 = (const float*)d_in[8];
  const float* tb1 = (const float*)d_in[9];
  const float* tW2 = (const float*)d_in[10];
  const float* tb2 = (const float*)d_in[11];
  const float* tW3 = (const float*)d_in[12];
  const float* tb3 = (const float*)d_in[13];
  bf16_t* ws = (bf16_t*)d_ws;            // needs 284 KB
  float* out = (float*)d_out;

  prep_weights<<<(WS_TOTAL + 255) / 256, 256, 0, stream>>>(sW1, sW2, sW3, tW1, tW2, tW3, ws);
  flow_kernel<<<256, 512, 0, stream>>>(e, sb1, sb2, sb3, tb1, tb2, tb3, ws, out);
}

// Round 4
// 455.071 us; speedup vs baseline: 1.0768x; 1.0768x over previous
//
#include <hip/hip_runtime.h>

// Problem constants
#define B_SZ 65536
#define NH   100

typedef __bf16 bf16_t;
typedef __bf16 bf16x8 __attribute__((ext_vector_type(8)));
typedef float  f32x4  __attribute__((ext_vector_type(4)));

// ---- d_ws bf16 fragment layout (elements), N padded to 112 (7 n-tiles) ----
// frag f=(nt*KC+kc): lane holds W[kc*32+Q*8+j][nt*16+c], j contiguous (b128)
#define SZ_W2 14336            // 7nt * 4kc * 512
#define SZ_W3 8192             // 4nt * 4kc * 512
#define SZ_W1 7168             // 7nt * 2kc * 512 (per net per z-block)
#define OFF_W3   28672         // after W2S,W2T
#define OFF_W1   45056         // after W3S,W3T; block b: S at +b*2*SZ_W1, T at +SZ_W1
#define WS_TOTAL 145408        // elements (290816 bytes)

__global__ void prep_weights(const float* __restrict__ sW1, const float* __restrict__ sW2,
                             const float* __restrict__ sW3, const float* __restrict__ tW1,
                             const float* __restrict__ tW2, const float* __restrict__ tW3,
                             bf16_t* __restrict__ ws) {
  int idx = blockIdx.x * 256 + threadIdx.x;
  if (idx >= WS_TOTAL) return;
  float v = 0.f;
  if (idx < 2 * SZ_W2) {                    // W2: [100,100] -> K128 x N112 frags
    const float* W = (idx < SZ_W2) ? sW2 : tW2;
    int l = (idx < SZ_W2) ? idx : idx - SZ_W2;
    int j = l & 7, ln = (l >> 3) & 63, kc = (l >> 9) & 3, nt = l >> 11;   // nt 0..6
    int k = kc * 32 + (ln >> 4) * 8 + j;
    int n = nt * 16 + (ln & 15);
    v = (k < NH && n < NH) ? W[k * NH + n] : 0.f;
  } else if (idx < OFF_W1) {                // W3: [100,64] -> K128 x N64 frags
    int l = idx - OFF_W3;
    const float* W = (l < SZ_W3) ? sW3 : tW3;
    l &= (SZ_W3 - 1);
    int j = l & 7, ln = (l >> 3) & 63, kc = (l >> 9) & 3, nt = l >> 11;   // nt 0..3
    int k = kc * 32 + (ln >> 4) * 8 + j;
    int n = nt * 16 + (ln & 15);
    v = (k < NH) ? W[k * 64 + n] : 0.f;
  } else {                                  // W1 blocks 0..6: [64,100] -> K64 x N112 frags
    int l = idx - OFF_W1;
    int b = l / (2 * SZ_W1);
    int r2 = l - b * 2 * SZ_W1;
    const float* W = (r2 < SZ_W1) ? sW1 : tW1;
    int w = (r2 < SZ_W1) ? r2 : r2 - SZ_W1;
    int j = w & 7, ln = (w >> 3) & 63, kc = (w >> 9) & 1, nt = w >> 10;   // nt 0..6
    int k = kc * 32 + (ln >> 4) * 8 + j;    // 0..63
    int n = nt * 16 + (ln & 15);
    v = (n < NH) ? W[(b * 64 + k) * NH + n] : 0.f;
  }
  ws[idx] = (bf16_t)v;
}

// async global->LDS 16B per lane: gptr per-lane, lptr wave-uniform base (+lane*16 implicit)
__device__ __forceinline__ void gload_lds16(const void* gptr, void* lptr) {
  __builtin_amdgcn_global_load_lds(
      (const __attribute__((address_space(1))) unsigned int*)gptr,
      (__attribute__((address_space(3))) unsigned int*)lptr, 16, 0, 0);
}

struct __align__(16) SMem {
  bf16_t w2[2 * SZ_W2];   // S at 0, T at SZ_W2           (57344 B)
  bf16_t w3[2 * SZ_W3];   // S at 0, T at SZ_W3           (32768 B)
  bf16_t w1[2 * SZ_W1];   // current z-block: S, T        (28672 B)
  bf16_t hb[8][16 * 136]; // per-wave transpose buffer    (34816 B)
};                        // total 153600 B -> 1 block/CU, 8 waves (2/SIMD)

// 256 blocks x 512 threads (8 waves); each wave owns 32 batch rows (2 m-tiles).
// All MFMA operands from LDS; W1 single-buffered, prefetched a full step ahead.
__global__ __launch_bounds__(512, 2) void flow_kernel(
    const float* __restrict__ e,
    const float* __restrict__ sb1, const float* __restrict__ sb2, const float* __restrict__ sb3,
    const float* __restrict__ tb1, const float* __restrict__ tb2, const float* __restrict__ tb3,
    const bf16_t* __restrict__ wf,
    float* __restrict__ out) {
  __shared__ SMem sm;

  const int tid  = threadIdx.x;
  const int wave = tid >> 6;
  const int lane = tid & 63;
  const int c    = lane & 15;   // C/D col, A-frag m-row
  const int Q    = lane >> 4;   // quad
  const int rowBase = blockIdx.x * 256 + wave * 32;

  bf16_t* const myh = &sm.hb[wave][0];

  // ---- initial load: W2S,W2T,W3S,W3T,W1(block0) = 118784 B = 116 x 1KB chunks
  {
    const char* g = (const char*)wf;
    char* l = (char*)&sm;
    #pragma unroll
    for (int t = 0; t < 14; ++t) {
      const int ch = t * 8 + wave;
      gload_lds16(g + ch * 1024 + lane * 16, l + ch * 1024);
    }
    if (wave < 4) {
      const int ch = 112 + wave;
      gload_lds16(g + ch * 1024 + lane * 16, l + ch * 1024);
    }
  }

  // ---- bias registers ----
  float b2S[7], b2T[7], b3S[4], b3T[4];
  #pragma unroll
  for (int nt = 0; nt < 7; ++nt) {
    const int n = nt * 16 + c;
    b2S[nt] = (n < NH) ? sb2[n] : 0.f;
    b2T[nt] = (n < NH) ? tb2[n] : 0.f;
  }
  #pragma unroll
  for (int nt = 0; nt < 4; ++nt) { b3S[nt] = sb3[nt * 16 + c]; b3T[nt] = tb3[nt * 16 + c]; }

  // persistent incremental layer-1 pre-activations (+b1), both nets
  f32x4 acc1S[2][7], acc1T[2][7];
  #pragma unroll
  for (int nt = 0; nt < 7; ++nt) {
    const int n = nt * 16 + c;
    const float b1s = (n < NH) ? sb1[n] : 0.f;
    const float b1t = (n < NH) ? tb1[n] : 0.f;
    const f32x4 vs = {b1s, b1s, b1s, b1s};
    const f32x4 vt = {b1t, b1t, b1t, b1t};
    #pragma unroll
    for (int mt = 0; mt < 2; ++mt) { acc1S[mt][nt] = vs; acc1T[mt][nt] = vt; }
  }
  float ldacc[2][4] = {0.f, 0.f, 0.f, 0.f, 0.f, 0.f, 0.f, 0.f};

  __syncthreads();   // initial weights + W1 block0 resident

  // one net: acc1 -> relu -> LDS -> A-frags -> L2 -> relu -> LDS -> A-frags -> L3 -> acc3
  auto run_net = [&](const f32x4 (&acc1)[2][7], const bf16_t* __restrict__ w2f,
                     const bf16_t* __restrict__ w3f, const float (&b2r)[7],
                     const float (&b3r)[4], f32x4 (&acc3)[2][4]) {
    f32x4 acc2[2][7];
    bf16x8 af[2][4];
    // L2 A-feed (h1), zero-pad cols 112..127 for the kc=3 chunk
    #pragma unroll
    for (int mt = 0; mt < 2; ++mt) {
      #pragma unroll
      for (int nt = 0; nt < 7; ++nt)
        #pragma unroll
        for (int r = 0; r < 4; ++r)
          myh[(Q * 4 + r) * 136 + nt * 16 + c] = (bf16_t)fmaxf(acc1[mt][nt][r], 0.f);
      #pragma unroll
      for (int r = 0; r < 4; ++r)
        myh[(Q * 4 + r) * 136 + 112 + c] = (bf16_t)0.f;
      #pragma unroll
      for (int kc = 0; kc < 4; ++kc)
        af[mt][kc] = *(const bf16x8*)(myh + c * 136 + kc * 32 + Q * 8);
    }
    #pragma unroll
    for (int nt = 0; nt < 7; ++nt) {
      const f32x4 bv = {b2r[nt], b2r[nt], b2r[nt], b2r[nt]};
      acc2[0][nt] = bv; acc2[1][nt] = bv;
    }
    #pragma unroll
    for (int nt = 0; nt < 7; ++nt)
      #pragma unroll
      for (int kc = 0; kc < 4; ++kc) {
        const bf16x8 bfr = *(const bf16x8*)(w2f + ((nt * 4 + kc) * 64 + lane) * 8);
        #pragma unroll
        for (int mt = 0; mt < 2; ++mt)
          acc2[mt][nt] = __builtin_amdgcn_mfma_f32_16x16x32_bf16(af[mt][kc], bfr, acc2[mt][nt], 0, 0, 0);
      }
    // L3 A-feed (h2); pad cols stay zero from h1 write
    #pragma unroll
    for (int mt = 0; mt < 2; ++mt) {
      #pragma unroll
      for (int nt = 0; nt < 7; ++nt)
        #pragma unroll
        for (int r = 0; r < 4; ++r)
          myh[(Q * 4 + r) * 136 + nt * 16 + c] = (bf16_t)fmaxf(acc2[mt][nt][r], 0.f);
      #pragma unroll
      for (int kc = 0; kc < 4; ++kc)
        af[mt][kc] = *(const bf16x8*)(myh + c * 136 + kc * 32 + Q * 8);
    }
    #pragma unroll
    for (int nt = 0; nt < 4; ++nt) {
      const f32x4 bv = {b3r[nt], b3r[nt], b3r[nt], b3r[nt]};
      acc3[0][nt] = bv; acc3[1][nt] = bv;
    }
    #pragma unroll
    for (int nt = 0; nt < 4; ++nt)
      #pragma unroll
      for (int kc = 0; kc < 4; ++kc) {
        const bf16x8 bfr = *(const bf16x8*)(w3f + ((nt * 4 + kc) * 64 + lane) * 8);
        #pragma unroll
        for (int mt = 0; mt < 2; ++mt)
          acc3[mt][nt] = __builtin_amdgcn_mfma_f32_16x16x32_bf16(af[mt][kc], bfr, acc3[mt][nt], 0, 0, 0);
      }
  };

  for (int i = 0; i < 8; ++i) {
    f32x4 acc3S[2][4], acc3T[2][4];
    run_net(acc1S, sm.w2, sm.w3, b2S, b3S, acc3S);

    // e for this step: loaded between net passes (short live range, T-pass hides latency)
    float ev[2][4][4];
    #pragma unroll
    for (int mt = 0; mt < 2; ++mt)
      #pragma unroll
      for (int r = 0; r < 4; ++r) {
        const int ebase = (rowBase + mt * 16 + Q * 4 + r) * 512 + i * 64;
        #pragma unroll
        for (int nt = 0; nt < 4; ++nt)
          ev[mt][r][nt] = e[ebase + nt * 16 + c];
      }

    run_net(acc1T, sm.w2 + SZ_W2, sm.w3 + SZ_W3, b2T, b3T, acc3T);

    // ---- epilogue: s,t = sigmoid; z = exp(s)*e + t; logdet += sum(s) ----
    bf16x8 zfa[2][2];
    #pragma unroll
    for (int mt = 0; mt < 2; ++mt) {
      #pragma unroll
      for (int r = 0; r < 4; ++r) {
        const int obase = (rowBase + mt * 16 + Q * 4 + r) * 512 + i * 64;
        float ssum = 0.f;
        #pragma unroll
        for (int nt = 0; nt < 4; ++nt) {
          const int col = nt * 16 + c;
          const float sv = 1.f / (1.f + __expf(-acc3S[mt][nt][r]));
          const float tv = 1.f / (1.f + __expf(-acc3T[mt][nt][r]));
          const float zv = __expf(sv) * ev[mt][r][nt] + tv;
          out[obase + col] = zv;
          myh[(Q * 4 + r) * 136 + col] = (bf16_t)zv;
          ssum += sv;
        }
        ssum += __shfl_xor(ssum, 1);
        ssum += __shfl_xor(ssum, 2);
        ssum += __shfl_xor(ssum, 4);
        ssum += __shfl_xor(ssum, 8);
        ldacc[mt][r] += ssum;
      }
      #pragma unroll
      for (int kc = 0; kc < 2; ++kc)
        zfa[mt][kc] = *(const bf16x8*)(myh + c * 136 + kc * 32 + Q * 8);
    }

    // ---- incremental layer-1 update: acc1 += z_i @ W1[block i] (from LDS) ----
    if (i < 7) {
      __syncthreads();   // (a) W1 block i resident (prefetched last step / init)
      #pragma unroll
      for (int nt = 0; nt < 7; ++nt)
        #pragma unroll
        for (int kc = 0; kc < 2; ++kc) {
          const bf16x8 bS = *(const bf16x8*)(sm.w1 + ((nt * 2 + kc) * 64 + lane) * 8);
          const bf16x8 bT = *(const bf16x8*)(sm.w1 + SZ_W1 + ((nt * 2 + kc) * 64 + lane) * 8);
          #pragma unroll
          for (int mt = 0; mt < 2; ++mt) {
            acc1S[mt][nt] = __builtin_amdgcn_mfma_f32_16x16x32_bf16(zfa[mt][kc], bS, acc1S[mt][nt], 0, 0, 0);
            acc1T[mt][nt] = __builtin_amdgcn_mfma_f32_16x16x32_bf16(zfa[mt][kc], bT, acc1T[mt][nt], 0, 0, 0);
          }
        }
      __syncthreads();   // (b) all waves done reading W1 block i
      if (i < 6) {       // prefetch W1 block i+1; hidden under next step's 2 net passes
        const char* g = (const char*)(wf + OFF_W1 + (i + 1) * 2 * SZ_W1);
        char* l = (char*)sm.w1;
        #pragma unroll
        for (int t = 0; t < 3; ++t) {
          const int ch = t * 8 + wave;
          gload_lds16(g + ch * 1024 + lane * 16, l + ch * 1024);
        }
        if (wave < 4) {
          const int ch = 24 + wave;
          gload_lds16(g + ch * 1024 + lane * 16, l + ch * 1024);
        }
      }
    }
  }

  // log_det: per (mt,r) replicated across 16 c-lanes; lane c==0 writes
  if (c == 0) {
    #pragma unroll
    for (int mt = 0; mt < 2; ++mt)
      #pragma unroll
      for (int r = 0; r < 4; ++r)
        out[B_SZ * 512 + rowBase + mt * 16 + Q * 4 + r] = ldacc[mt][r];
  }
}

extern "C" void kernel_launch(void* const* d_in, const int* in_sizes, int n_in,
                              void* d_out, int out_size, void* d_ws, size_t ws_size,
                              hipStream_t stream) {
  (void)in_sizes; (void)n_in; (void)out_size; (void)ws_size;
  const float* e   = (const float*)d_in[0];
  // d_in[1] is C (fixed strict-upper-triangular structure; encoded in the algorithm)
  const float* sW1 = (const float*)d_in[2];
  const float* sb1 = (const float*)d_in[3];
  const float* sW2 = (const float*)d_in[4];
  const float* sb2 = (const float*)d_in[5];
  const float* sW3 = (const float*)d_in[6];
  const float* sb3 = (const float*)d_in[7];
  const float* tW1 = (const float*)d_in[8];
  const float* tb1 = (const float*)d_in[9];
  const float* tW2 = (const float*)d_in[10];
  const float* tb2 = (const float*)d_in[11];
  const float* tW3 = (const float*)d_in[12];
  const float* tb3 = (const float*)d_in[13];
  bf16_t* ws = (bf16_t*)d_ws;            // needs 284 KB
  float* out = (float*)d_out;

  prep_weights<<<(WS_TOTAL + 255) / 256, 256, 0, stream>>>(sW1, sW2, sW3, tW1, tW2, tW3, ws);
  flow_kernel<<<256, 512, 0, stream>>>(e, sb1, sb2, sb3, tb1, tb2, tb3, ws, out);
}

// Round 5
// 335.902 us; speedup vs baseline: 1.4589x; 1.3548x over previous
//
#include <hip/hip_runtime.h>

// Problem constants
#define B_SZ 65536
#define NH   100

typedef __bf16 bf16_t;
typedef __bf16 bf16x2 __attribute__((ext_vector_type(2)));
typedef __bf16 bf16x8 __attribute__((ext_vector_type(8)));
typedef float  f32x4  __attribute__((ext_vector_type(4)));

// ---- d_ws layout ----
// bf16 region: A-fragment (weight-transposed) tiles for mfma_f32_16x16x32_bf16.
// frag (mt,kc): lane L=(Q=L>>4,c=L&15) holds A[m=mt*16+c][k=kc*32+Q*8+j], j=0..7.
#define SZ_W2 14336            // 7 m-tiles * 4 kc * 512
#define SZ_W3 8192             // 4 m-tiles * 4 kc * 512
#define SZ_W1 7168             // 7 m-tiles * 2 kc * 512 (per net per z-block)
#define OFF_W3   28672         // elems; after W2S,W2T
#define OFF_W1   45056         // elems; block b: S at +b*2*SZ_W1, T at +SZ_W1
#define WS_TOTAL 145408        // bf16 elems (290816 bytes)
// float region at ws+WS_TOTAL: [b2S 112][b2T 112][b3S 64][b3T 64][b1S 112][b1T 112]

__global__ void prep_weights(const float* __restrict__ sW1, const float* __restrict__ sW2,
                             const float* __restrict__ sW3, const float* __restrict__ tW1,
                             const float* __restrict__ tW2, const float* __restrict__ tW3,
                             bf16_t* __restrict__ ws) {
  int idx = blockIdx.x * 256 + threadIdx.x;
  if (idx >= WS_TOTAL) return;
  float v = 0.f;
  if (idx < 2 * SZ_W2) {                    // W2^T: A[m=out][k=in], 112x128
    const float* W = (idx < SZ_W2) ? sW2 : tW2;
    int l = (idx < SZ_W2) ? idx : idx - SZ_W2;
    int j = l & 7, ln = (l >> 3) & 63, kc = (l >> 9) & 3, mt = l >> 11;   // mt 0..6
    int k = kc * 32 + (ln >> 4) * 8 + j;    // in-hidden
    int m = mt * 16 + (ln & 15);            // out-hidden
    v = (k < NH && m < NH) ? W[k * NH + m] : 0.f;
  } else if (idx < OFF_W1) {                // W3^T: A[m=out 64][k=in], 64x128
    int l = idx - OFF_W3;
    const float* W = (l < SZ_W3) ? sW3 : tW3;
    l &= (SZ_W3 - 1);
    int j = l & 7, ln = (l >> 3) & 63, kc = (l >> 9) & 3, mt = l >> 11;   // mt 0..3
    int k = kc * 32 + (ln >> 4) * 8 + j;
    int m = mt * 16 + (ln & 15);
    v = (k < NH) ? W[k * 64 + m] : 0.f;
  } else {                                  // W1^T blocks 0..6: A[m=out 112][k=z 64]
    int l = idx - OFF_W1;
    int b = l / (2 * SZ_W1);
    int r2 = l - b * 2 * SZ_W1;
    const float* W = (r2 < SZ_W1) ? sW1 : tW1;
    int w = (r2 < SZ_W1) ? r2 : r2 - SZ_W1;
    int j = w & 7, ln = (w >> 3) & 63, kc = (w >> 9) & 1, mt = w >> 10;   // mt 0..6
    int k = kc * 32 + (ln >> 4) * 8 + j;    // 0..63
    int m = mt * 16 + (ln & 15);
    v = (m < NH) ? W[(b * 64 + k) * NH + m] : 0.f;
  }
  ws[idx] = (bf16_t)v;
}

__global__ void prep_bias(const float* __restrict__ sb1, const float* __restrict__ sb2,
                          const float* __restrict__ sb3, const float* __restrict__ tb1,
                          const float* __restrict__ tb2, const float* __restrict__ tb3,
                          float* __restrict__ fb) {
  int t = threadIdx.x;                      // single block, 576 threads
  if (t < 112)       fb[t] = (t < NH) ? sb2[t] : 0.f;
  else if (t < 224)  fb[t] = (t - 112 < NH) ? tb2[t - 112] : 0.f;
  else if (t < 288)  fb[t] = sb3[t - 224];
  else if (t < 352)  fb[t] = tb3[t - 288];
  else if (t < 464)  fb[t] = (t - 352 < NH) ? sb1[t - 352] : 0.f;
  else if (t < 576)  fb[t] = (t - 464 < NH) ? tb1[t - 464] : 0.f;
}

// async global->LDS 16B/lane: gptr per-lane, lptr wave-uniform base (+lane*16 implicit)
__device__ __forceinline__ void gload_lds16(const void* gptr, void* lptr) {
  __builtin_amdgcn_global_load_lds(
      (const __attribute__((address_space(1))) unsigned int*)gptr,
      (__attribute__((address_space(3))) unsigned int*)lptr, 16, 0, 0);
}

__device__ __forceinline__ unsigned pk2(float a, float b) {
  bf16x2 t = {(bf16_t)a, (bf16_t)b};
  return __builtin_bit_cast(unsigned, t);
}

// Build B-frag B[k=Q*8+j][n=c] from two C-layout tiles (packed: pk[0]=rows(0,1),
// pk[1]=rows(2,3) of each lane's quad). Element j: src lane = c+16*((Q&1)*2+(j>>2)),
// tile = lo for Q<2 else hi, reg = j&3.
__device__ __forceinline__ bf16x8 build_bfrag(const unsigned* pkLo, const unsigned* pkHi,
                                              int idx0, int idx1, bool hiSel) {
  int l0 = __builtin_amdgcn_ds_bpermute(idx0, (int)pkLo[0]);
  int h0 = __builtin_amdgcn_ds_bpermute(idx0, (int)pkHi[0]);
  int l1 = __builtin_amdgcn_ds_bpermute(idx0, (int)pkLo[1]);
  int h1 = __builtin_amdgcn_ds_bpermute(idx0, (int)pkHi[1]);
  int l2 = __builtin_amdgcn_ds_bpermute(idx1, (int)pkLo[0]);
  int h2 = __builtin_amdgcn_ds_bpermute(idx1, (int)pkHi[0]);
  int l3 = __builtin_amdgcn_ds_bpermute(idx1, (int)pkLo[1]);
  int h3 = __builtin_amdgcn_ds_bpermute(idx1, (int)pkHi[1]);
  union { unsigned u[4]; bf16x8 v; } r;
  r.u[0] = (unsigned)(hiSel ? h0 : l0);
  r.u[1] = (unsigned)(hiSel ? h1 : l1);
  r.u[2] = (unsigned)(hiSel ? h2 : l2);
  r.u[3] = (unsigned)(hiSel ? h3 : l3);
  return r.v;
}

struct __align__(16) SMem {
  bf16_t w2[2 * SZ_W2];       // 57344 B
  bf16_t w3[2 * SZ_W3];       // 32768 B
  bf16_t w1[2][2 * SZ_W1];    // double-buffered current z-block (S,T)  57344 B
  float  bias[512];           // b2S,b2T,b3S,b3T (+unused tail)          2048 B
};                            // 149504 B -> 1 block/CU, 8 waves (2/SIMD)

// 256 blocks x 512 threads; wave owns 32 batch COLUMNS (2 n-tiles).
// All GEMMs as Y = W^T @ X: A=weights (LDS frags), B=activations (built in-reg
// via ds_bpermute from C-layout). No LDS transpose buffer; 1 barrier/step.
__global__ __launch_bounds__(512, 2) void flow_kernel(
    const float* __restrict__ e,
    const bf16_t* __restrict__ wf,
    const float* __restrict__ fb,
    float* __restrict__ out) {
  __shared__ SMem sm;

  const int tid  = threadIdx.x;
  const int wave = tid >> 6;
  const int lane = tid & 63;
  const int c    = lane & 15;          // batch col within n-tile
  const int Q    = lane >> 4;
  const int rowBase = blockIdx.x * 256 + wave * 32;

  const int  idx0  = 4 * (c + 32 * (Q & 1));   // bpermute byte-indices
  const int  idx1  = idx0 + 64;
  const bool hiSel = (Q >= 2);

  // ---- initial stage: W2,W3 (90112B) + W1 blk0 -> buf0 (28672B) + bias (2KB)
  {
    const char* g = (const char*)wf;
    char* l = (char*)&sm;
    const char* gb = (const char*)fb;
    #pragma unroll
    for (int t = 0; t < 15; ++t) {
      const int ch = t * 8 + wave;
      if (ch < 116)      gload_lds16(g + ch * 1024 + lane * 16, l + ch * 1024);
      else if (ch < 118) gload_lds16(gb + (ch - 116) * 1024 + lane * 16,
                                     (char*)sm.bias + (ch - 116) * 1024);
    }
  }

  // persistent layer-1 pre-activations (+b1), C-layout [mt][7 tiles]
  f32x4 acc1S[2][7], acc1T[2][7];
  #pragma unroll
  for (int th = 0; th < 7; ++th) {
    const f32x4 vs = *(const f32x4*)(fb + 352 + th * 16 + Q * 4);
    const f32x4 vt = *(const f32x4*)(fb + 464 + th * 16 + Q * 4);
    acc1S[0][th] = vs; acc1S[1][th] = vs;
    acc1T[0][th] = vt; acc1T[1][th] = vt;
  }
  float ldacc[2] = {0.f, 0.f};

  __syncthreads();   // weights + blk0 + bias resident

  const float* lb2S = sm.bias;
  const float* lb2T = sm.bias + 112;
  const float* lb3S = sm.bias + 224;
  const float* lb3T = sm.bias + 288;

  // acc1 -> relu/pack -> (bperm B-frags) -> L2 -> relu/pack -> L3 -> acc3
  auto run_net = [&](const f32x4 (&acc1)[2][7], const bf16_t* __restrict__ w2f,
                     const bf16_t* __restrict__ w3f, const float* __restrict__ lb2,
                     const float* __restrict__ lb3, f32x4 (&acc3)[2][4]) {
    unsigned pk[2][7][2];
    #pragma unroll
    for (int mt = 0; mt < 2; ++mt)
      #pragma unroll
      for (int th = 0; th < 7; ++th) {
        pk[mt][th][0] = pk2(fmaxf(acc1[mt][th][0], 0.f), fmaxf(acc1[mt][th][1], 0.f));
        pk[mt][th][1] = pk2(fmaxf(acc1[mt][th][2], 0.f), fmaxf(acc1[mt][th][3], 0.f));
      }
    f32x4 acc2[2][7];
    #pragma unroll
    for (int th = 0; th < 7; ++th) {
      const f32x4 bv = *(const f32x4*)(lb2 + th * 16 + Q * 4);
      acc2[0][th] = bv; acc2[1][th] = bv;
    }
    #pragma unroll
    for (int kc = 0; kc < 4; ++kc) {
      const int tlo = kc * 2, thi = (kc * 2 + 1 > 6) ? 6 : kc * 2 + 1;  // k>=100 hits zero A
      const bf16x8 b0 = build_bfrag(pk[0][tlo], pk[0][thi], idx0, idx1, hiSel);
      const bf16x8 b1 = build_bfrag(pk[1][tlo], pk[1][thi], idx0, idx1, hiSel);
      #pragma unroll
      for (int th = 0; th < 7; ++th) {
        const bf16x8 A = *(const bf16x8*)(w2f + ((th * 4 + kc) * 64 + lane) * 8);
        acc2[0][th] = __builtin_amdgcn_mfma_f32_16x16x32_bf16(A, b0, acc2[0][th], 0, 0, 0);
        acc2[1][th] = __builtin_amdgcn_mfma_f32_16x16x32_bf16(A, b1, acc2[1][th], 0, 0, 0);
      }
    }
    // layer 3
    #pragma unroll
    for (int mt = 0; mt < 2; ++mt)
      #pragma unroll
      for (int th = 0; th < 7; ++th) {
        pk[mt][th][0] = pk2(fmaxf(acc2[mt][th][0], 0.f), fmaxf(acc2[mt][th][1], 0.f));
        pk[mt][th][1] = pk2(fmaxf(acc2[mt][th][2], 0.f), fmaxf(acc2[mt][th][3], 0.f));
      }
    #pragma unroll
    for (int ot = 0; ot < 4; ++ot) {
      const f32x4 bv = *(const f32x4*)(lb3 + ot * 16 + Q * 4);
      acc3[0][ot] = bv; acc3[1][ot] = bv;
    }
    #pragma unroll
    for (int kc = 0; kc < 4; ++kc) {
      const int tlo = kc * 2, thi = (kc * 2 + 1 > 6) ? 6 : kc * 2 + 1;
      const bf16x8 b0 = build_bfrag(pk[0][tlo], pk[0][thi], idx0, idx1, hiSel);
      const bf16x8 b1 = build_bfrag(pk[1][tlo], pk[1][thi], idx0, idx1, hiSel);
      #pragma unroll
      for (int ot = 0; ot < 4; ++ot) {
        const bf16x8 A = *(const bf16x8*)(w3f + ((ot * 4 + kc) * 64 + lane) * 8);
        acc3[0][ot] = __builtin_amdgcn_mfma_f32_16x16x32_bf16(A, b0, acc3[0][ot], 0, 0, 0);
        acc3[1][ot] = __builtin_amdgcn_mfma_f32_16x16x32_bf16(A, b1, acc3[1][ot], 0, 0, 0);
      }
    }
  };

  for (int i = 0; i < 8; ++i) {
    f32x4 acc3S[2][4], acc3T[2][4];
    run_net(acc1S, sm.w2,         sm.w3,         lb2S, lb3S, acc3S);
    run_net(acc1T, sm.w2 + SZ_W2, sm.w3 + SZ_W3, lb2T, lb3T, acc3T);

    // ---- epilogue: s,t=sigmoid; z=exp(s)*e+t (f32x4 rows per lane); logdet ----
    unsigned zpk[2][4][2];
    #pragma unroll
    for (int mt = 0; mt < 2; ++mt) {
      #pragma unroll
      for (int ot = 0; ot < 4; ++ot) {
        const int off = (rowBase + mt * 16 + c) * 512 + i * 64 + ot * 16 + Q * 4;
        const f32x4 ev = *(const f32x4*)(e + off);
        f32x4 zv;
        float ss = 0.f;
        #pragma unroll
        for (int r = 0; r < 4; ++r) {
          const float sv = 1.f / (1.f + __expf(-acc3S[mt][ot][r]));
          const float tv = 1.f / (1.f + __expf(-acc3T[mt][ot][r]));
          zv[r] = __expf(sv) * ev[r] + tv;
          ss += sv;
        }
        __builtin_nontemporal_store(zv, (f32x4*)(out + off));
        zpk[mt][ot][0] = pk2(zv[0], zv[1]);
        zpk[mt][ot][1] = pk2(zv[2], zv[3]);
        ldacc[mt] += ss;
      }
    }

    // ---- incremental layer-1 update: acc1 += W1_i^T @ z_i ----
    if (i < 7) {
      __syncthreads();   // blk i resident in buf[i&1] (all waves' chunks drained)
      const bf16_t* __restrict__ w1b = sm.w1[i & 1];
      #pragma unroll
      for (int kc = 0; kc < 2; ++kc) {
        const bf16x8 b0 = build_bfrag(zpk[0][kc * 2], zpk[0][kc * 2 + 1], idx0, idx1, hiSel);
        const bf16x8 b1 = build_bfrag(zpk[1][kc * 2], zpk[1][kc * 2 + 1], idx0, idx1, hiSel);
        #pragma unroll
        for (int th = 0; th < 7; ++th) {
          const bf16x8 AS = *(const bf16x8*)(w1b + ((th * 2 + kc) * 64 + lane) * 8);
          const bf16x8 AT = *(const bf16x8*)(w1b + SZ_W1 + ((th * 2 + kc) * 64 + lane) * 8);
          acc1S[0][th] = __builtin_amdgcn_mfma_f32_16x16x32_bf16(AS, b0, acc1S[0][th], 0, 0, 0);
          acc1S[1][th] = __builtin_amdgcn_mfma_f32_16x16x32_bf16(AS, b1, acc1S[1][th], 0, 0, 0);
          acc1T[0][th] = __builtin_amdgcn_mfma_f32_16x16x32_bf16(AT, b0, acc1T[0][th], 0, 0, 0);
          acc1T[1][th] = __builtin_amdgcn_mfma_f32_16x16x32_bf16(AT, b1, acc1T[1][th], 0, 0, 0);
        }
      }
      if (i < 6) {   // prefetch blk i+1 -> buf[(i+1)&1]; consumed after NEXT barrier
        const char* g = (const char*)wf + 90112 + (i + 1) * 28672;
        char* l = (char*)sm.w1[(i + 1) & 1];
        #pragma unroll
        for (int t = 0; t < 4; ++t) {
          const int ch = t * 8 + wave;
          if (ch < 28) gload_lds16(g + ch * 1024 + lane * 16, l + ch * 1024);
        }
      }
    }
  }

  // log_det: reduce over Q (lanes c, c+16, c+32, c+48); Q==0 lanes write
  #pragma unroll
  for (int mt = 0; mt < 2; ++mt) {
    float v = ldacc[mt];
    v += __shfl_xor(v, 16);
    v += __shfl_xor(v, 32);
    if (Q == 0) out[B_SZ * 512 + rowBase + mt * 16 + c] = v;
  }
}

extern "C" void kernel_launch(void* const* d_in, const int* in_sizes, int n_in,
                              void* d_out, int out_size, void* d_ws, size_t ws_size,
                              hipStream_t stream) {
  (void)in_sizes; (void)n_in; (void)out_size; (void)ws_size;
  const float* e   = (const float*)d_in[0];
  // d_in[1] is C (fixed strict-upper-triangular structure; encoded in the algorithm)
  const float* sW1 = (const float*)d_in[2];
  const float* sb1 = (const float*)d_in[3];
  const float* sW2 = (const float*)d_in[4];
  const float* sb2 = (const float*)d_in[5];
  const float* sW3 = (const float*)d_in[6];
  const float* sb3 = (const float*)d_in[7];
  const float* tW1 = (const float*)d_in[8];
  const float* tb1 = (const float*)d_in[9];
  const float* tW2 = (const float*)d_in[10];
  const float* tb2 = (const float*)d_in[11];
  const float* tW3 = (const float*)d_in[12];
  const float* tb3 = (const float*)d_in[13];
  bf16_t* ws = (bf16_t*)d_ws;                  // needs ~287 KB
  float*  fb = (float*)(ws + WS_TOTAL);
  float* out = (float*)d_out;

  prep_weights<<<(WS_TOTAL + 255) / 256, 256, 0, stream>>>(sW1, sW2, sW3, tW1, tW2, tW3, ws);
  prep_bias<<<1, 576, 0, stream>>>(sb1, sb2, sb3, tb1, tb2, tb3, fb);
  flow_kernel<<<256, 512, 0, stream>>>(e, ws, fb, out);
}